// Round 3
// baseline (191.149 us; speedup 1.0000x reference)
//
#include <hip/hip_runtime.h>
#include <hip/hip_bf16.h>

// Problem constants (from reference): B=64, IMG=1024, IND=64, E=4, FF=16
// I/O contract (established rounds 0-2): ALL inputs fp32, OUTPUT fp32
// (reference returns float32 softmax; round-2 bf16 writes left the second
// half of the 768-byte buffer zero -> baseline absmax reproduced exactly).
#define B_        64
#define IMG_      1024
#define IND_      64
#define NTHR      128
#define IMG_SPLIT 8                     // blocks per image batch
#define IMG_ROWS  (IMG_ / IMG_SPLIT)    // 128 Q rows per block == NTHR

// LDS weight-slab offsets (floats)
enum {
  W_IN = 0, B_IN = 4, QKV_W = 8, QKV_B = 56, O_W = 68, O_B = 84,
  LN1G = 88, LN1B = 92, FF1W = 96, FF1B = 160, FF2W = 176, FF2B = 240,
  LN2G = 244, LN2B = 248, W_OUT = 252, B_OUT = 256, WTOT = 257
};

struct KArgs {
  const float* in[36];
  float* ws_img;   // [B, IMG] f32
  float* ws_ind;   // [B, IND] f32
};

__device__ __forceinline__ void stage(float* dst, const float* src, int n, int tid) {
  for (int i = tid; i < n; i += NTHR) dst[i] = src[i];
}

__global__ __launch_bounds__(NTHR) void fused_enc(KArgs A) {
  const int blk = blockIdx.x;
  const int tid = threadIdx.x;
  const bool is_img = blk < B_ * IMG_SPLIT;

  __shared__ float w[WTOT];
  __shared__ float kv[IMG_][8];   // [seq][k0..3, v0..3]

  int batch, row0, S, tb;
  const float* xin;
  if (is_img) {
    batch = blk >> 3; row0 = (blk & 7) * IMG_ROWS; S = IMG_;
    xin = A.in[0] + batch * IMG_;      // image_embeds [B,IMG,1]
    tb = 10;                           // t1_* weights start
  } else {
    batch = blk - B_ * IMG_SPLIT; row0 = 0; S = IND_;
    xin = A.in[1] + batch * IND_;      // indicator_embeds [B,1,IND] (== swapaxes view)
    tb = 22;                           // t2_* weights start
  }

  // ---- stage all weights for this path into LDS ----
  stage(w + W_IN,  A.in[is_img ? 2 : 4], 4,  tid);
  stage(w + B_IN,  A.in[is_img ? 3 : 5], 4,  tid);
  stage(w + W_OUT, A.in[is_img ? 6 : 8], 4,  tid);
  stage(w + B_OUT, A.in[is_img ? 7 : 9], 1,  tid);
  stage(w + QKV_W, A.in[tb + 0], 48, tid);
  stage(w + QKV_B, A.in[tb + 1], 12, tid);
  stage(w + O_W,   A.in[tb + 2], 16, tid);
  stage(w + O_B,   A.in[tb + 3], 4,  tid);
  stage(w + LN1G,  A.in[tb + 4], 4,  tid);
  stage(w + LN1B,  A.in[tb + 5], 4,  tid);
  stage(w + FF1W,  A.in[tb + 6], 64, tid);
  stage(w + FF1B,  A.in[tb + 7], 16, tid);
  stage(w + FF2W,  A.in[tb + 8], 64, tid);
  stage(w + FF2B,  A.in[tb + 9], 4,  tid);
  stage(w + LN2G,  A.in[tb + 10], 4, tid);
  stage(w + LN2B,  A.in[tb + 11], 4, tid);
  __syncthreads();

  // ---- stage K,V for the whole sequence into LDS ----
  for (int r = tid; r < S; r += NTHR) {
    const float iv = xin[r];
    float x[4];
#pragma unroll
    for (int e = 0; e < 4; e++) x[e] = iv * w[W_IN + e] + w[B_IN + e];
#pragma unroll
    for (int j = 0; j < 4; j++) {
      float kk = w[QKV_B + 4 + j], vv = w[QKV_B + 8 + j];
#pragma unroll
      for (int e = 0; e < 4; e++) {
        kk += x[e] * w[QKV_W + e * 12 + 4 + j];
        vv += x[e] * w[QKV_W + e * 12 + 8 + j];
      }
      kv[r][j] = kk; kv[r][4 + j] = vv;
    }
  }
  __syncthreads();

  // ---- one Q row per thread: attention + o-proj + LN1 + FF + LN2 + out-proj ----
  const int r = row0 + tid;
  const bool active = is_img ? true : (tid < IND_);
  if (active) {
    const float iv = xin[r];
    float x[4], q[4];
#pragma unroll
    for (int e = 0; e < 4; e++) x[e] = iv * w[W_IN + e] + w[B_IN + e];
#pragma unroll
    for (int j = 0; j < 4; j++) {
      float qq = w[QKV_B + j];
#pragma unroll
      for (int e = 0; e < 4; e++) qq += x[e] * w[QKV_W + e * 12 + j];
      q[j] = qq * 0.5f;   // fold 1/sqrt(E) into q
    }

    // streaming softmax (scores are provably small; no max-shift needed in f32)
    float l = 0.f, a0 = 0.f, a1 = 0.f, a2 = 0.f, a3 = 0.f;
    for (int t = 0; t < S; t++) {
      const float4 kk = *reinterpret_cast<const float4*>(&kv[t][0]);
      const float4 vv = *reinterpret_cast<const float4*>(&kv[t][4]);
      const float s = q[0] * kk.x + q[1] * kk.y + q[2] * kk.z + q[3] * kk.w;
      const float p = __expf(s);
      l += p;
      a0 += p * vv.x; a1 += p * vv.y; a2 += p * vv.z; a3 += p * vv.w;
    }
    const float rl = 1.0f / l;
    float at[4] = {a0 * rl, a1 * rl, a2 * rl, a3 * rl};

    // attn @ o_w + o_b, residual
    float h[4];
#pragma unroll
    for (int j = 0; j < 4; j++) {
      float o = w[O_B + j];
#pragma unroll
      for (int f = 0; f < 4; f++) o += at[f] * w[O_W + f * 4 + j];
      h[j] = x[j] + o;
    }
    // LN1 over E=4
    {
      const float m = 0.25f * (h[0] + h[1] + h[2] + h[3]);
      float v = 0.f;
#pragma unroll
      for (int j = 0; j < 4; j++) { const float d = h[j] - m; v += d * d; }
      const float rs = rsqrtf(v * 0.25f + 1e-5f);
#pragma unroll
      for (int j = 0; j < 4; j++) h[j] = (h[j] - m) * rs * w[LN1G + j] + w[LN1B + j];
    }
    // FF: relu(h @ ff1 + b1) @ ff2 + b2, residual
    float f2[4] = {w[FF2B + 0], w[FF2B + 1], w[FF2B + 2], w[FF2B + 3]};
#pragma unroll
    for (int t = 0; t < 16; t++) {
      float u = w[FF1B + t];
#pragma unroll
      for (int j = 0; j < 4; j++) u += h[j] * w[FF1W + j * 16 + t];
      u = fmaxf(u, 0.f);
#pragma unroll
      for (int j = 0; j < 4; j++) f2[j] += u * w[FF2W + t * 4 + j];
    }
    float h2[4];
#pragma unroll
    for (int j = 0; j < 4; j++) h2[j] = h[j] + f2[j];
    // LN2
    {
      const float m = 0.25f * (h2[0] + h2[1] + h2[2] + h2[3]);
      float v = 0.f;
#pragma unroll
      for (int j = 0; j < 4; j++) { const float d = h2[j] - m; v += d * d; }
      const float rs = rsqrtf(v * 0.25f + 1e-5f);
#pragma unroll
      for (int j = 0; j < 4; j++) h2[j] = (h2[j] - m) * rs * w[LN2G + j] + w[LN2B + j];
    }
    // out-proj to scalar
    float out = w[B_OUT];
#pragma unroll
    for (int j = 0; j < 4; j++) out += h2[j] * w[W_OUT + j];

    if (is_img) A.ws_img[batch * IMG_ + r] = out;
    else        A.ws_ind[batch * IND_ + r] = out;
  }
}

__global__ __launch_bounds__(256) void cls_head(const float* __restrict__ img_o,
                                                const float* __restrict__ ind_o,
                                                const float* __restrict__ w_cls,
                                                const float* __restrict__ b_cls,
                                                float* __restrict__ out) {
  const int b = blockIdx.x, tid = threadIdx.x;
  float p0 = 0.f, p1 = 0.f, p2 = 0.f;
  const float* xi = img_o + b * IMG_;
  for (int i = tid; i < IMG_; i += 256) {
    const float v = xi[i];
    p0 += v * w_cls[i * 3 + 0];
    p1 += v * w_cls[i * 3 + 1];
    p2 += v * w_cls[i * 3 + 2];
  }
  if (tid < IND_) {
    const float v = ind_o[b * IND_ + tid];
    const int j = IMG_ + tid;
    p0 += v * w_cls[j * 3 + 0];
    p1 += v * w_cls[j * 3 + 1];
    p2 += v * w_cls[j * 3 + 2];
  }
  // wave64 shuffle reduce, then cross-wave via LDS
  for (int off = 32; off > 0; off >>= 1) {
    p0 += __shfl_down(p0, off, 64);
    p1 += __shfl_down(p1, off, 64);
    p2 += __shfl_down(p2, off, 64);
  }
  __shared__ float red[4][3];
  if ((tid & 63) == 0) { const int wv = tid >> 6; red[wv][0] = p0; red[wv][1] = p1; red[wv][2] = p2; }
  __syncthreads();
  if (tid == 0) {
    float z0 = red[0][0] + red[1][0] + red[2][0] + red[3][0] + b_cls[0];
    float z1 = red[0][1] + red[1][1] + red[2][1] + red[3][1] + b_cls[1];
    float z2 = red[0][2] + red[1][2] + red[2][2] + red[3][2] + b_cls[2];
    const float mx = fmaxf(z0, fmaxf(z1, z2));
    const float e0 = __expf(z0 - mx), e1 = __expf(z1 - mx), e2 = __expf(z2 - mx);
    const float rs = 1.f / (e0 + e1 + e2);
    out[b * 3 + 0] = e0 * rs;
    out[b * 3 + 1] = e1 * rs;
    out[b * 3 + 2] = e2 * rs;
  }
}

extern "C" void kernel_launch(void* const* d_in, const int* in_sizes, int n_in,
                              void* d_out, int out_size, void* d_ws, size_t ws_size,
                              hipStream_t stream) {
  KArgs A;
  for (int i = 0; i < 36; i++) A.in[i] = (const float*)d_in[i];
  A.ws_img = (float*)d_ws;
  A.ws_ind = A.ws_img + B_ * IMG_;

  fused_enc<<<B_ * IMG_SPLIT + B_, NTHR, 0, stream>>>(A);
  cls_head<<<B_, 256, 0, stream>>>(A.ws_img, A.ws_ind, A.in[34], A.in[35],
                                   (float*)d_out);
}

// Round 5
// 151.178 us; speedup vs baseline: 1.2644x; 1.2644x over previous
//
#include <hip/hip_runtime.h>

// B=64, IMG=1024, IND=64, E=4, FF=16. Inputs fp32, output fp32.
// Key identity: tokens are scalar iv through affine stem -> q/k/v rows are
// affine in iv; softmax row weight = exp(alpha_r*iv_t) (row-const factor
// cancels); attention output = vd*rho + vb with rho = S1/S0,
// S0 = sum_t exp(alpha_r iv_t), S1 = sum_t iv_t exp(alpha_r iv_t).
#define B_    64
#define IMG_  1024
#define IND_  64
#define NTHR  256
#define IMG_BPB 16                 // img blocks per batch (64 rows each)

enum {
  W_IN = 0, B_IN = 4, QKV_W = 8, QKV_B = 56, O_W = 68, O_B = 84,
  LN1G = 88, LN1B = 92, FF1W = 96, FF1B = 160, FF2W = 176, FF2B = 240,
  LN2G = 244, LN2B = 248, W_OUT = 252, B_OUT = 256, WTOT = 257
};

struct KArgs {
  const float* in[36];
  float* ws_img;   // [B, IMG] f32
  float* ws_ind;   // [B, IND] f32
};

__device__ __forceinline__ void stage(float* dst, const float* src, int n, int tid) {
  for (int i = tid; i < n; i += NTHR) dst[i] = src[i];
}

__global__ __launch_bounds__(NTHR) void fused_enc(KArgs A) {
  const int blk = blockIdx.x;
  const int tid = threadIdx.x;
  const bool is_img = blk < B_ * IMG_BPB;

  __shared__ float w[WTOT];
  __shared__ float iv[IMG_];

  int batch, row, S, tb;
  const float* xin;
  if (is_img) {
    batch = blk >> 4; row = ((blk & 15) << 6) + (tid >> 2); S = IMG_;
    xin = A.in[0] + batch * IMG_; tb = 10;
  } else {
    batch = blk - B_ * IMG_BPB; row = tid >> 2; S = IND_;
    xin = A.in[1] + batch * IND_; tb = 22;
  }

  // ---- stage weights + the scalar token sequence ----
  stage(w + W_IN,  A.in[is_img ? 2 : 4], 4,  tid);
  stage(w + B_IN,  A.in[is_img ? 3 : 5], 4,  tid);
  stage(w + W_OUT, A.in[is_img ? 6 : 8], 4,  tid);
  stage(w + B_OUT, A.in[is_img ? 7 : 9], 1,  tid);
  stage(w + QKV_W, A.in[tb + 0], 48, tid);
  stage(w + QKV_B, A.in[tb + 1], 12, tid);
  stage(w + O_W,   A.in[tb + 2], 16, tid);
  stage(w + O_B,   A.in[tb + 3], 4,  tid);
  stage(w + LN1G,  A.in[tb + 4], 4,  tid);
  stage(w + LN1B,  A.in[tb + 5], 4,  tid);
  stage(w + FF1W,  A.in[tb + 6], 64, tid);
  stage(w + FF1B,  A.in[tb + 7], 16, tid);
  stage(w + FF2W,  A.in[tb + 8], 64, tid);
  stage(w + FF2B,  A.in[tb + 9], 4,  tid);
  stage(w + LN2G,  A.in[tb + 10], 4, tid);
  stage(w + LN2B,  A.in[tb + 11], 4, tid);
  for (int i = tid; i < S; i += NTHR) iv[i] = xin[i];
  __syncthreads();

  // ---- derived affine constants (uniform; broadcast LDS reads) ----
  float qd[4], qb[4], kd[4], kb[4], vd[4], vb[4];
#pragma unroll
  for (int j = 0; j < 4; j++) {
    float a0 = 0.f, a1 = 0.f, a2 = 0.f, b0 = 0.f, b1 = 0.f, b2 = 0.f;
#pragma unroll
    for (int e = 0; e < 4; e++) {
      const float we = w[W_IN + e], be = w[B_IN + e];
      a0 += we * w[QKV_W + e * 12 + j];      b0 += be * w[QKV_W + e * 12 + j];
      a1 += we * w[QKV_W + e * 12 + 4 + j];  b1 += be * w[QKV_W + e * 12 + 4 + j];
      a2 += we * w[QKV_W + e * 12 + 8 + j];  b2 += be * w[QKV_W + e * 12 + 8 + j];
    }
    qd[j] = a0; qb[j] = b0 + w[QKV_B + j];
    kd[j] = a1; kb[j] = b1 + w[QKV_B + 4 + j];
    vd[j] = a2; vb[j] = b2 + w[QKV_B + 8 + j];
  }
  float c1 = 0.f, c0 = 0.f;
#pragma unroll
  for (int j = 0; j < 4; j++) { c1 += qd[j] * kd[j]; c0 += qb[j] * kd[j]; }
  // h = HA*iv + HB*rho + HC (HA = w_in row)
  float HB[4], HC[4];
#pragma unroll
  for (int j = 0; j < 4; j++) {
    float s1 = 0.f, s2 = 0.f;
#pragma unroll
    for (int f = 0; f < 4; f++) {
      s1 += vd[f] * w[O_W + f * 4 + j];
      s2 += vb[f] * w[O_W + f * 4 + j];
    }
    HB[j] = s1; HC[j] = w[B_IN + j] + s2 + w[O_B + j];
  }

  const float ivr = iv[row];
  // exp2-ready row coefficient: score(t) = alpha*iv_t (+const that cancels)
  const float ah = 0.5f * 1.4426950408889634f * (c1 * ivr + c0);

  // ---- 4-lane split streaming softmax sums ----
  const int c = tid & 3;
  const int nch = S >> 2;      // float4 chunks
  float S0 = 0.f, S1 = 0.f;
  for (int ci = c; ci < nch; ci += 4) {
    const float4 t4 = *reinterpret_cast<const float4*>(&iv[ci << 2]);
    float p;
    p = exp2f(ah * t4.x); S0 += p; S1 = fmaf(p, t4.x, S1);
    p = exp2f(ah * t4.y); S0 += p; S1 = fmaf(p, t4.y, S1);
    p = exp2f(ah * t4.z); S0 += p; S1 = fmaf(p, t4.z, S1);
    p = exp2f(ah * t4.w); S0 += p; S1 = fmaf(p, t4.w, S1);
  }
  // reduce across the 4 lanes of this row
  S0 += __shfl_xor(S0, 1); S1 += __shfl_xor(S1, 1);
  S0 += __shfl_xor(S0, 2); S1 += __shfl_xor(S1, 2);
  const float rho = S1 / S0;

  // ---- per-row tail (redundant on 4 lanes; lane c==0 writes) ----
  float h[4];
#pragma unroll
  for (int j = 0; j < 4; j++) h[j] = w[W_IN + j] * ivr + HB[j] * rho + HC[j];
  {
    const float m = 0.25f * (h[0] + h[1] + h[2] + h[3]);
    float v = 0.f;
#pragma unroll
    for (int j = 0; j < 4; j++) { const float d = h[j] - m; v += d * d; }
    const float rs = rsqrtf(v * 0.25f + 1e-5f);
#pragma unroll
    for (int j = 0; j < 4; j++) h[j] = (h[j] - m) * rs * w[LN1G + j] + w[LN1B + j];
  }
  float f2[4] = {w[FF2B + 0], w[FF2B + 1], w[FF2B + 2], w[FF2B + 3]};
#pragma unroll
  for (int t = 0; t < 16; t++) {
    float u = w[FF1B + t];
#pragma unroll
    for (int j = 0; j < 4; j++) u += h[j] * w[FF1W + j * 16 + t];
    u = fmaxf(u, 0.f);
#pragma unroll
    for (int j = 0; j < 4; j++) f2[j] += u * w[FF2W + t * 4 + j];
  }
  float h2[4];
#pragma unroll
  for (int j = 0; j < 4; j++) h2[j] = h[j] + f2[j];
  {
    const float m = 0.25f * (h2[0] + h2[1] + h2[2] + h2[3]);
    float v = 0.f;
#pragma unroll
    for (int j = 0; j < 4; j++) { const float d = h2[j] - m; v += d * d; }
    const float rs = rsqrtf(v * 0.25f + 1e-5f);
#pragma unroll
    for (int j = 0; j < 4; j++) h2[j] = (h2[j] - m) * rs * w[LN2G + j] + w[LN2B + j];
  }
  float out = w[B_OUT];
#pragma unroll
  for (int j = 0; j < 4; j++) out += h2[j] * w[W_OUT + j];

  if (c == 0) {
    if (is_img) A.ws_img[batch * IMG_ + row] = out;
    else        A.ws_ind[batch * IND_ + row] = out;
  }
}

__global__ __launch_bounds__(256) void cls_head(const float* __restrict__ img_o,
                                                const float* __restrict__ ind_o,
                                                const float* __restrict__ w_cls,
                                                const float* __restrict__ b_cls,
                                                float* __restrict__ out) {
  const int b = blockIdx.x, tid = threadIdx.x;
  float p0 = 0.f, p1 = 0.f, p2 = 0.f;
  const float* xi = img_o + b * IMG_;
  for (int i = tid; i < IMG_; i += 256) {
    const float v = xi[i];
    p0 += v * w_cls[i * 3 + 0];
    p1 += v * w_cls[i * 3 + 1];
    p2 += v * w_cls[i * 3 + 2];
  }
  if (tid < IND_) {
    const float v = ind_o[b * IND_ + tid];
    const int j = IMG_ + tid;
    p0 += v * w_cls[j * 3 + 0];
    p1 += v * w_cls[j * 3 + 1];
    p2 += v * w_cls[j * 3 + 2];
  }
  for (int off = 32; off > 0; off >>= 1) {
    p0 += __shfl_down(p0, off, 64);
    p1 += __shfl_down(p1, off, 64);
    p2 += __shfl_down(p2, off, 64);
  }
  __shared__ float red[4][3];
  if ((tid & 63) == 0) { const int wv = tid >> 6; red[wv][0] = p0; red[wv][1] = p1; red[wv][2] = p2; }
  __syncthreads();
  if (tid == 0) {
    float z0 = red[0][0] + red[1][0] + red[2][0] + red[3][0] + b_cls[0];
    float z1 = red[0][1] + red[1][1] + red[2][1] + red[3][1] + b_cls[1];
    float z2 = red[0][2] + red[1][2] + red[2][2] + red[3][2] + b_cls[2];
    const float mx = fmaxf(z0, fmaxf(z1, z2));
    const float e0 = __expf(z0 - mx), e1 = __expf(z1 - mx), e2 = __expf(z2 - mx);
    const float rs = 1.f / (e0 + e1 + e2);
    out[b * 3 + 0] = e0 * rs;
    out[b * 3 + 1] = e1 * rs;
    out[b * 3 + 2] = e2 * rs;
  }
}

extern "C" void kernel_launch(void* const* d_in, const int* in_sizes, int n_in,
                              void* d_out, int out_size, void* d_ws, size_t ws_size,
                              hipStream_t stream) {
  KArgs A;
  for (int i = 0; i < 36; i++) A.in[i] = (const float*)d_in[i];
  A.ws_img = (float*)d_ws;
  A.ws_ind = A.ws_img + B_ * IMG_;

  fused_enc<<<B_ * IMG_BPB + B_, NTHR, 0, stream>>>(A);
  cls_head<<<B_, 256, 0, stream>>>(A.ws_img, A.ws_ind, A.in[34], A.in[35],
                                   (float*)d_out);
}

// Round 6
// 149.596 us; speedup vs baseline: 1.2778x; 1.0106x over previous
//
#include <hip/hip_runtime.h>

// B=64, IMG=1024, IND=64, E=4, FF=16. Inputs fp32, output fp32.
// Algebraic collapse (validated round 5, absmax 0.0): tokens are scalar iv
// through an affine stem -> scores s(r,t) = alpha_r*iv_t + beta_r, beta_r
// cancels in softmax; attention out = vd*rho + vb, rho = S1/S0.
// This round: 1-block prep kernel derives all constants once into a ws slab;
// fused_enc's per-block preamble becomes one coalesced 192-float read.
#define B_    64
#define IMG_  1024
#define IND_  64
#define NTHR  256
#define IMG_BPB 16                 // img blocks per batch (64 rows each)

// slab layout (floats), one 192-float slab per path
enum {
  P_C1 = 0, P_C0 = 1, P_HA = 2, P_HB = 6, P_HC = 10,
  P_LN1G = 14, P_LN1B = 18, P_FF1W = 22, P_FF1B = 86, P_FF2W = 102,
  P_FF2B = 166, P_LN2G = 170, P_LN2B = 174, P_WOUT = 178, P_BOUT = 182,
  P_SLAB = 192
};

struct KArgs {
  const float* in[36];
  float* slab;     // [2][192] f32
  float* ws_img;   // [B, IMG] f32
  float* ws_ind;   // [B, IND] f32
};

__global__ __launch_bounds__(128) void prep(KArgs A) {
  const int path = threadIdx.x >> 6;    // 0 = img (t1), 1 = ind (t2)
  const int lane = threadIdx.x & 63;
  const int tb = path ? 22 : 10;
  float* s = A.slab + path * P_SLAB;
  const float* w_in  = A.in[path ? 4 : 2];
  const float* b_in  = A.in[path ? 5 : 3];
  const float* w_out = A.in[path ? 8 : 6];
  const float* b_out = A.in[path ? 9 : 7];

  // pass-through copies
  s[P_FF1W + lane] = A.in[tb + 6][lane];   // 64
  s[P_FF2W + lane] = A.in[tb + 8][lane];   // 64
  if (lane < 16) s[P_FF1B + lane] = A.in[tb + 7][lane];
  if (lane < 4) {
    s[P_HA + lane]   = w_in[lane];
    s[P_WOUT + lane] = w_out[lane];
    s[P_LN1G + lane] = A.in[tb + 4][lane];
    s[P_LN1B + lane] = A.in[tb + 5][lane];
    s[P_FF2B + lane] = A.in[tb + 9][lane];
    s[P_LN2G + lane] = A.in[tb + 10][lane];
    s[P_LN2B + lane] = A.in[tb + 11][lane];
  }
  if (lane == 0) {
    s[P_BOUT] = b_out[0];
    const float* qkv_w = A.in[tb + 0];   // [4][12]
    const float* qkv_b = A.in[tb + 1];   // [12]
    const float* o_w   = A.in[tb + 2];   // [4][4]
    const float* o_b   = A.in[tb + 3];   // [4]
    float qd[4], qb[4], kd[4], vd[4], vb[4];
    for (int j = 0; j < 4; j++) {
      float a0 = 0.f, a1 = 0.f, a2 = 0.f, b0 = 0.f, b1 = 0.f, b2 = 0.f;
      for (int e = 0; e < 4; e++) {
        const float we = w_in[e], be = b_in[e];
        a0 += we * qkv_w[e * 12 + j];      b0 += be * qkv_w[e * 12 + j];
        a1 += we * qkv_w[e * 12 + 4 + j];  b1 += be * qkv_w[e * 12 + 4 + j];
        a2 += we * qkv_w[e * 12 + 8 + j];  b2 += be * qkv_w[e * 12 + 8 + j];
      }
      qd[j] = a0; qb[j] = b0 + qkv_b[j];
      kd[j] = a1;                          // kb folds into the cancelled const
      vd[j] = a2; vb[j] = b2 + qkv_b[8 + j];
    }
    float c1 = 0.f, c0 = 0.f;
    for (int j = 0; j < 4; j++) { c1 += qd[j] * kd[j]; c0 += qb[j] * kd[j]; }
    s[P_C1] = c1; s[P_C0] = c0;
    for (int j = 0; j < 4; j++) {
      float s1 = 0.f, s2 = 0.f;
      for (int f = 0; f < 4; f++) {
        s1 += vd[f] * o_w[f * 4 + j];
        s2 += vb[f] * o_w[f * 4 + j];
      }
      s[P_HB + j] = s1;
      s[P_HC + j] = b_in[j] + s2 + o_b[j];
    }
  }
}

__global__ __launch_bounds__(NTHR) void fused_enc(KArgs A) {
  const int blk = blockIdx.x;
  const int tid = threadIdx.x;
  const bool is_img = blk < B_ * IMG_BPB;

  __shared__ float w[P_SLAB];
  __shared__ float iv[IMG_];

  int batch, row, S;
  const float* xin;
  if (is_img) {
    batch = blk >> 4; row = ((blk & 15) << 6) + (tid >> 2); S = IMG_;
    xin = A.in[0] + batch * IMG_;
  } else {
    batch = blk - B_ * IMG_BPB; row = tid >> 2; S = IND_;
    xin = A.in[1] + batch * IND_;
  }

  if (tid < P_SLAB) w[tid] = A.slab[(is_img ? 0 : P_SLAB) + tid];
  for (int i = tid; i < S; i += NTHR) iv[i] = xin[i];
  __syncthreads();

  const float ivr = iv[row];
  const float ah = 0.5f * 1.4426950408889634f * (w[P_C1] * ivr + w[P_C0]);

  // ---- 4-lane split streaming softmax sums ----
  const int c = tid & 3;
  const int nch = S >> 2;      // float4 chunks
  float S0 = 0.f, S1 = 0.f;
  for (int ci = c; ci < nch; ci += 4) {
    const float4 t4 = *reinterpret_cast<const float4*>(&iv[ci << 2]);
    float p;
    p = exp2f(ah * t4.x); S0 += p; S1 = fmaf(p, t4.x, S1);
    p = exp2f(ah * t4.y); S0 += p; S1 = fmaf(p, t4.y, S1);
    p = exp2f(ah * t4.z); S0 += p; S1 = fmaf(p, t4.z, S1);
    p = exp2f(ah * t4.w); S0 += p; S1 = fmaf(p, t4.w, S1);
  }
  S0 += __shfl_xor(S0, 1); S1 += __shfl_xor(S1, 1);
  S0 += __shfl_xor(S0, 2); S1 += __shfl_xor(S1, 2);
  const float rho = S1 / S0;

  // ---- per-row tail (redundant on 4 lanes; lane c==0 writes) ----
  float h[4];
#pragma unroll
  for (int j = 0; j < 4; j++) h[j] = w[P_HA + j] * ivr + w[P_HB + j] * rho + w[P_HC + j];
  {
    const float m = 0.25f * (h[0] + h[1] + h[2] + h[3]);
    float v = 0.f;
#pragma unroll
    for (int j = 0; j < 4; j++) { const float d = h[j] - m; v += d * d; }
    const float rs = rsqrtf(v * 0.25f + 1e-5f);
#pragma unroll
    for (int j = 0; j < 4; j++) h[j] = (h[j] - m) * rs * w[P_LN1G + j] + w[P_LN1B + j];
  }
  float f2[4] = {w[P_FF2B + 0], w[P_FF2B + 1], w[P_FF2B + 2], w[P_FF2B + 3]};
#pragma unroll
  for (int t = 0; t < 16; t++) {
    float u = w[P_FF1B + t];
#pragma unroll
    for (int j = 0; j < 4; j++) u += h[j] * w[P_FF1W + j * 16 + t];
    u = fmaxf(u, 0.f);
#pragma unroll
    for (int j = 0; j < 4; j++) f2[j] += u * w[P_FF2W + t * 4 + j];
  }
  float h2[4];
#pragma unroll
  for (int j = 0; j < 4; j++) h2[j] = h[j] + f2[j];
  {
    const float m = 0.25f * (h2[0] + h2[1] + h2[2] + h2[3]);
    float v = 0.f;
#pragma unroll
    for (int j = 0; j < 4; j++) { const float d = h2[j] - m; v += d * d; }
    const float rs = rsqrtf(v * 0.25f + 1e-5f);
#pragma unroll
    for (int j = 0; j < 4; j++) h2[j] = (h2[j] - m) * rs * w[P_LN2G + j] + w[P_LN2B + j];
  }
  float out = w[P_BOUT];
#pragma unroll
  for (int j = 0; j < 4; j++) out += h2[j] * w[P_WOUT + j];

  if (c == 0) {
    if (is_img) A.ws_img[batch * IMG_ + row] = out;
    else        A.ws_ind[batch * IND_ + row] = out;
  }
}

__global__ __launch_bounds__(256) void cls_head(const float* __restrict__ img_o,
                                                const float* __restrict__ ind_o,
                                                const float* __restrict__ w_cls,
                                                const float* __restrict__ b_cls,
                                                float* __restrict__ out) {
  const int b = blockIdx.x, tid = threadIdx.x;
  float p0 = 0.f, p1 = 0.f, p2 = 0.f;
  const float* xi = img_o + b * IMG_;
  for (int i = tid; i < IMG_; i += 256) {
    const float v = xi[i];
    p0 += v * w_cls[i * 3 + 0];
    p1 += v * w_cls[i * 3 + 1];
    p2 += v * w_cls[i * 3 + 2];
  }
  if (tid < IND_) {
    const float v = ind_o[b * IND_ + tid];
    const int j = IMG_ + tid;
    p0 += v * w_cls[j * 3 + 0];
    p1 += v * w_cls[j * 3 + 1];
    p2 += v * w_cls[j * 3 + 2];
  }
  for (int off = 32; off > 0; off >>= 1) {
    p0 += __shfl_down(p0, off, 64);
    p1 += __shfl_down(p1, off, 64);
    p2 += __shfl_down(p2, off, 64);
  }
  __shared__ float red[4][3];
  if ((tid & 63) == 0) { const int wv = tid >> 6; red[wv][0] = p0; red[wv][1] = p1; red[wv][2] = p2; }
  __syncthreads();
  if (tid == 0) {
    float z0 = red[0][0] + red[1][0] + red[2][0] + red[3][0] + b_cls[0];
    float z1 = red[0][1] + red[1][1] + red[2][1] + red[3][1] + b_cls[1];
    float z2 = red[0][2] + red[1][2] + red[2][2] + red[3][2] + b_cls[2];
    const float mx = fmaxf(z0, fmaxf(z1, z2));
    const float e0 = __expf(z0 - mx), e1 = __expf(z1 - mx), e2 = __expf(z2 - mx);
    const float rs = 1.f / (e0 + e1 + e2);
    out[b * 3 + 0] = e0 * rs;
    out[b * 3 + 1] = e1 * rs;
    out[b * 3 + 2] = e2 * rs;
  }
}

extern "C" void kernel_launch(void* const* d_in, const int* in_sizes, int n_in,
                              void* d_out, int out_size, void* d_ws, size_t ws_size,
                              hipStream_t stream) {
  KArgs A;
  for (int i = 0; i < 36; i++) A.in[i] = (const float*)d_in[i];
  A.slab   = (float*)d_ws;                 // 2*192 floats (padded to 512)
  A.ws_img = (float*)d_ws + 512;
  A.ws_ind = A.ws_img + B_ * IMG_;

  prep<<<1, 128, 0, stream>>>(A);
  fused_enc<<<B_ * IMG_BPB + B_, NTHR, 0, stream>>>(A);
  cls_head<<<B_, 256, 0, stream>>>(A.ws_img, A.ws_ind, A.in[34], A.in[35],
                                   (float*)d_out);
}